// Round 9
// baseline (76.902 us; speedup 1.0000x reference)
//
#include <hip/hip_runtime.h>
#include <hip/hip_bf16.h>

// Problem constants
#define NA 32      // agents per graph
#define NACT 64    // actions
#define NIN 128    // in_dim
#define NOUT 128   // out_dim
#define NB 256     // graphs
// Inputs f32. Outputs f32: obs_final [8192,32,192] then w_out [8192,32,1].

// ---------------------------------------------------------------------------
// Fused kernel: one block per graph (grid=256, block=1024, 16 waves).
// Key idea this round: the obs region (134 MB of the 201 MB output) depends
// only on obs_proc, and dst-row k's obs slice is the SAME obs4[tid] for every
// k. So: one float4 load per thread at entry + one store per projection-loop
// iteration -> the obs write stream drains under phase-1 compute instead of
// serializing after it. Phase 2 handles only the z_mix region.
// ---------------------------------------------------------------------------
__global__ __launch_bounds__(1024) void fused_kernel(
    const float* __restrict__ h,
    const float* __restrict__ Wk, const float* __restrict__ bk,
    const float* __restrict__ Wq, const float* __restrict__ bq,
    const float* __restrict__ policies, const float* __restrict__ actions,
    const float* __restrict__ obs, const float* __restrict__ noise,
    float* __restrict__ out, float* __restrict__ w_out)
{
    __shared__ float sh[NA][NIN];         // 16 KB
    __shared__ float sK[NA][NOUT + 4];    // 16.5 KB
    __shared__ float sQ[NA][NOUT + 4];    // 16.5 KB
    __shared__ float sw[NA][NA];          // 4 KB
    __shared__ float spi[NA][NACT];       // 8 KB
    __shared__ float sac[NA][NACT];       // 8 KB   (total 69.5 KB)

    const int b   = blockIdx.x;
    const int tid = threadIdx.x;

    // ---- early global loads (issue all, then stage)
    const float4 hv4  = reinterpret_cast<const float4*>(h   + (size_t)b * NA * NIN)[tid];
    const float4 obsv = reinterpret_cast<const float4*>(obs + (size_t)b * NA * NIN)[tid];
    float4 pav;
    if (tid < 512) {
        pav = reinterpret_cast<const float4*>(policies + (size_t)b * 2048)[tid];
    } else {
        pav = reinterpret_cast<const float4*>(actions  + (size_t)b * 2048)[tid - 512];
    }

    reinterpret_cast<float4*>(&sh[0][0])[tid] = hv4;
    if (tid < 512) reinterpret_cast<float4*>(&spi[0][0])[tid] = pav;
    else           reinterpret_cast<float4*>(&sac[0][0])[tid - 512] = pav;
    __syncthreads();

    float4* og4 = reinterpret_cast<float4*>(out) + (size_t)b * NA * 1536;  // graph base
    const int obs_off = ((tid >> 5) * 48) + (tid & 31);  // t-slot*48 + col-group

    // ---- phase 1a: projection (tx = out-dim 0..127, ty = node-group 0..7)
    //      with one obs-row store embedded per r-iteration (32 total = 32 rows)
    {
        const int tx = tid & 127;
        const int ty = tid >> 7;
        float ak[4], aq[4];
        const float bkv = bk[tx];
        const float bqv = bq[tx];
#pragma unroll
        for (int s = 0; s < 4; ++s) { ak[s] = bkv; aq[s] = bqv; }
        for (int r = 0; r < NIN; r += 4) {
            const float wk0 = Wk[(r + 0) * NOUT + tx];
            const float wk1 = Wk[(r + 1) * NOUT + tx];
            const float wk2 = Wk[(r + 2) * NOUT + tx];
            const float wk3 = Wk[(r + 3) * NOUT + tx];
            const float wq0 = Wq[(r + 0) * NOUT + tx];
            const float wq1 = Wq[(r + 1) * NOUT + tx];
            const float wq2 = Wq[(r + 2) * NOUT + tx];
            const float wq3 = Wq[(r + 3) * NOUT + tx];
#pragma unroll
            for (int s = 0; s < 4; ++s) {
                const int n = ty * 4 + s;
                const float4 hv = *reinterpret_cast<const float4*>(&sh[n][r]);
                ak[s] = fmaf(hv.x, wk0, fmaf(hv.y, wk1, fmaf(hv.z, wk2, fmaf(hv.w, wk3, ak[s]))));
                aq[s] = fmaf(hv.x, wq0, fmaf(hv.y, wq1, fmaf(hv.z, wq2, fmaf(hv.w, wq3, aq[s]))));
            }
            // obs store for dst row (r>>2): pure register store, streams under compute
            og4[(r >> 2) * 1536 + obs_off] = obsv;
        }
#pragma unroll
        for (int s = 0; s < 4; ++s) {
            const int n = ty * 4 + s;
            sK[n][tx] = ak[s];
            sQ[n][tx] = aq[s];
        }
    }
    __syncthreads();

    // ---- phase 1b: scores + softmax (i = tid>>5 dst, j = tid&31 src)
    {
        const int i = tid >> 5;
        const int j = tid & 31;
        float sc = 0.f;
        for (int r = 0; r < NOUT; r += 4) {
            const float4 qv = *reinterpret_cast<const float4*>(&sQ[i][r]);
            const float4 kv = *reinterpret_cast<const float4*>(&sK[j][r]);
            sc = fmaf(qv.x, kv.x, fmaf(qv.y, kv.y, fmaf(qv.z, kv.z, fmaf(qv.w, kv.w, sc))));
        }
        sc *= 0.08838834764831845f;  // 1/sqrt(128)

        float m = sc;
#pragma unroll
        for (int off = 16; off >= 1; off >>= 1) m = fmaxf(m, __shfl_xor(m, off));
        const float e = __expf(sc - m);
        float ssum = e;
#pragma unroll
        for (int off = 16; off >= 1; off >>= 1) ssum += __shfl_xor(ssum, off);
        const float w = e / ssum;

        sw[i][j] = w;
        w_out[(size_t)b * (NA * NA) + tid] = w;
    }
    __syncthreads();   // last barrier — phase 2 is barrier-free

    // ---- phase 2: z_mix region only; wave wv owns dst rows 2wv, 2wv+1
    const int wv   = tid >> 6;    // wave 0..15
    const int lane = tid & 63;
    const int qq   = lane >> 4;   // t-quarter 0..3
    const int cg   = lane & 15;   // col group (4 floats)
    const int c0   = cg * 4;

#pragma unroll
    for (int ii = 0; ii < 2; ++ii) {
        const int i = wv * 2 + ii;
        float4* out4 = og4 + (size_t)i * 1536;

        float S0 = 0.f, S1 = 0.f, S2 = 0.f, S3 = 0.f;
        float y[8][4];
        const float* nzb = noise + (((size_t)(b * NA + i)) * 32 + qq * 8) * 64 + c0;
#pragma unroll
        for (int tt = 0; tt < 8; ++tt) {
            const int t = qq * 8 + tt;
            const float wt = sw[i][t];
            const float4 p4 = *reinterpret_cast<const float4*>(&spi[t][c0]);
            const float4 a4 = *reinterpret_cast<const float4*>(&sac[t][c0]);
            const float4 n4 = *reinterpret_cast<const float4*>(nzb + tt * 64);
            float z;
            z = fmaf(wt, a4.x - p4.x, p4.x) + n4.x; S0 += z; y[tt][0] = p4.x - z;
            z = fmaf(wt, a4.y - p4.y, p4.y) + n4.y; S1 += z; y[tt][1] = p4.y - z;
            z = fmaf(wt, a4.z - p4.z, p4.z) + n4.z; S2 += z; y[tt][2] = p4.z - z;
            z = fmaf(wt, a4.w - p4.w, p4.w) + n4.w; S3 += z; y[tt][3] = p4.w - z;
        }
        S0 += __shfl_xor(S0, 16); S0 += __shfl_xor(S0, 32);
        S1 += __shfl_xor(S1, 16); S1 += __shfl_xor(S1, 32);
        S2 += __shfl_xor(S2, 16); S2 += __shfl_xor(S2, 32);
        S3 += __shfl_xor(S3, 16); S3 += __shfl_xor(S3, 32);

#pragma unroll
        for (int tt = 0; tt < 8; ++tt) {
            const int t = qq * 8 + tt;
            float4 o;
            o.x = (S0 + y[tt][0]) * (1.0f / NA);
            o.y = (S1 + y[tt][1]) * (1.0f / NA);
            o.z = (S2 + y[tt][2]) * (1.0f / NA);
            o.w = (S3 + y[tt][3]) * (1.0f / NA);
            out4[t * 48 + 32 + cg] = o;
        }
    }
}

extern "C" void kernel_launch(void* const* d_in, const int* in_sizes, int n_in,
                              void* d_out, int out_size, void* d_ws, size_t ws_size,
                              hipStream_t stream) {
    const float* h        = (const float*)d_in[0];
    const float* policies = (const float*)d_in[1];
    const float* actions  = (const float*)d_in[2];
    const float* obs_proc = (const float*)d_in[3];
    const float* noise    = (const float*)d_in[4];
    const float* Wk       = (const float*)d_in[5];
    const float* bk       = (const float*)d_in[6];
    const float* Wq       = (const float*)d_in[7];
    const float* bq       = (const float*)d_in[8];

    float* out = (float*)d_out;
    float* obs_final = out;                                      // [8192,32,192]
    float* w_out = out + (size_t)NB * NA * NA * (NIN + NACT);    // [8192,32,1]

    fused_kernel<<<NB, 1024, 0, stream>>>(h, Wk, bk, Wq, bq,
                                          policies, actions, obs_proc, noise,
                                          obs_final, w_out);
}

// Round 10
// 63.957 us; speedup vs baseline: 1.2024x; 1.2024x over previous
//
#include <hip/hip_runtime.h>
#include <hip/hip_bf16.h>

// Problem constants
#define NA 32      // agents per graph
#define NACT 64    // actions
#define NIN 128    // in_dim
#define NOUT 128   // out_dim
#define NB 256     // graphs
// Inputs f32. Outputs f32: obs_final [8192,32,192] then w_out [8192,32,1].

// ---------------------------------------------------------------------------
// K1: mixed-block kernel, 256 threads/block.
//   blocks 0..255     : qk for graph bid -> writes w (f32) to w_out region.
//   blocks 256..8447  : copy obs region of dst row (bid-256)  [134 MB stream]
// The copy blocks keep HBM write BW saturated while qk blocks compute.
// ---------------------------------------------------------------------------
__global__ __launch_bounds__(256) void k1_qk_obscopy(
    const float* __restrict__ h,
    const float* __restrict__ Wk, const float* __restrict__ bk,
    const float* __restrict__ Wq, const float* __restrict__ bq,
    const float* __restrict__ obs,
    float* __restrict__ out, float* __restrict__ w_out)
{
    __shared__ float sh[NA][NIN];         // 16 KB
    __shared__ float sK[NA][NOUT + 4];    // 16.5 KB
    __shared__ float sQ[NA][NOUT + 4];    // 16.5 KB

    const int bid = blockIdx.x;
    const int tid = threadIdx.x;

    if (bid >= NB) {
        // ---- obs-copy block: dst row gr = bid-256; out row = 32 t-slots x 48 f4
        const int gr = bid - NB;
        const int b  = gr >> 5;
        const float4* so4 = reinterpret_cast<const float4*>(obs + (size_t)b * NA * NIN);
        float4* out4 = reinterpret_cast<float4*>(out) + (size_t)gr * 1536;
#pragma unroll
        for (int k = 0; k < 4; ++k) {
            const int m  = tid + 256 * k;   // 0..1023
            const int t2 = m >> 5;
            const int nn = m & 31;
            out4[t2 * 48 + nn] = so4[t2 * 32 + nn];
        }
        return;
    }

    // ---- qk block for graph g
    const int g = bid;

    // stage h (1024 f4, 4 per thread)
    {
        const float4* hs = reinterpret_cast<const float4*>(h + (size_t)g * NA * NIN);
        float4* shl = reinterpret_cast<float4*>(&sh[0][0]);
#pragma unroll
        for (int k = 0; k < 4; ++k) { const int m = tid + 256 * k; shl[m] = hs[m]; }
    }
    __syncthreads();

    // projection: txg = tid&31 (4 out-dims txg*4..+3), ty = tid>>5 (nodes ty*4..+3)
    {
        const int txg = tid & 31;
        const int ty  = tid >> 5;
        float4 kacc[4], qacc[4];
        const float4 bk4 = *reinterpret_cast<const float4*>(bk + txg * 4);
        const float4 bq4 = *reinterpret_cast<const float4*>(bq + txg * 4);
#pragma unroll
        for (int s = 0; s < 4; ++s) { kacc[s] = bk4; qacc[s] = bq4; }

        for (int r = 0; r < NIN; r += 4) {
            float4 wk[4], wq[4];
#pragma unroll
            for (int rr = 0; rr < 4; ++rr) {
                wk[rr] = *reinterpret_cast<const float4*>(Wk + (size_t)(r + rr) * NOUT + txg * 4);
                wq[rr] = *reinterpret_cast<const float4*>(Wq + (size_t)(r + rr) * NOUT + txg * 4);
            }
#pragma unroll
            for (int s = 0; s < 4; ++s) {
                const float4 hv = *reinterpret_cast<const float4*>(&sh[ty * 4 + s][r]);
                kacc[s].x = fmaf(hv.x, wk[0].x, fmaf(hv.y, wk[1].x, fmaf(hv.z, wk[2].x, fmaf(hv.w, wk[3].x, kacc[s].x))));
                kacc[s].y = fmaf(hv.x, wk[0].y, fmaf(hv.y, wk[1].y, fmaf(hv.z, wk[2].y, fmaf(hv.w, wk[3].y, kacc[s].y))));
                kacc[s].z = fmaf(hv.x, wk[0].z, fmaf(hv.y, wk[1].z, fmaf(hv.z, wk[2].z, fmaf(hv.w, wk[3].z, kacc[s].z))));
                kacc[s].w = fmaf(hv.x, wk[0].w, fmaf(hv.y, wk[1].w, fmaf(hv.z, wk[2].w, fmaf(hv.w, wk[3].w, kacc[s].w))));
                qacc[s].x = fmaf(hv.x, wq[0].x, fmaf(hv.y, wq[1].x, fmaf(hv.z, wq[2].x, fmaf(hv.w, wq[3].x, qacc[s].x))));
                qacc[s].y = fmaf(hv.x, wq[0].y, fmaf(hv.y, wq[1].y, fmaf(hv.z, wq[2].y, fmaf(hv.w, wq[3].y, qacc[s].y))));
                qacc[s].z = fmaf(hv.x, wq[0].z, fmaf(hv.y, wq[1].z, fmaf(hv.z, wq[2].z, fmaf(hv.w, wq[3].z, qacc[s].z))));
                qacc[s].w = fmaf(hv.x, wq[0].w, fmaf(hv.y, wq[1].w, fmaf(hv.z, wq[2].w, fmaf(hv.w, wq[3].w, qacc[s].w))));
            }
        }
#pragma unroll
        for (int s = 0; s < 4; ++s) {
            *reinterpret_cast<float4*>(&sK[ty * 4 + s][txg * 4]) = kacc[s];
            *reinterpret_cast<float4*>(&sQ[ty * 4 + s][txg * 4]) = qacc[s];
        }
    }
    __syncthreads();

    // scores + softmax: i = tid>>3 (dst row), jg = tid&7 (4 src j's)
    {
        const int i  = tid >> 3;
        const int jg = tid & 7;
        float sc[4] = {0.f, 0.f, 0.f, 0.f};
        for (int r = 0; r < NOUT; r += 4) {
            const float4 qv = *reinterpret_cast<const float4*>(&sQ[i][r]);
#pragma unroll
            for (int jj = 0; jj < 4; ++jj) {
                const float4 kv = *reinterpret_cast<const float4*>(&sK[jg * 4 + jj][r]);
                sc[jj] = fmaf(qv.x, kv.x, fmaf(qv.y, kv.y, fmaf(qv.z, kv.z, fmaf(qv.w, kv.w, sc[jj]))));
            }
        }
#pragma unroll
        for (int jj = 0; jj < 4; ++jj) sc[jj] *= 0.08838834764831845f;  // 1/sqrt(128)

        float m = fmaxf(fmaxf(sc[0], sc[1]), fmaxf(sc[2], sc[3]));
        m = fmaxf(m, __shfl_xor(m, 1));
        m = fmaxf(m, __shfl_xor(m, 2));
        m = fmaxf(m, __shfl_xor(m, 4));
        float e[4], ssum;
#pragma unroll
        for (int jj = 0; jj < 4; ++jj) e[jj] = __expf(sc[jj] - m);
        ssum = e[0] + e[1] + e[2] + e[3];
        ssum += __shfl_xor(ssum, 1);
        ssum += __shfl_xor(ssum, 2);
        ssum += __shfl_xor(ssum, 4);
        const float inv = 1.0f / ssum;

        *reinterpret_cast<float4*>(w_out + ((size_t)g * NA + i) * NA + jg * 4) =
            make_float4(e[0] * inv, e[1] * inv, e[2] * inv, e[3] * inv);
    }
}

// ---------------------------------------------------------------------------
// K2: z_mix region only. 2048 blocks x 256 (4 waves); wave wv owns dst row
// gr = blk*4+wv. Round-8 verified wave body (qq/cg split, shfl_xor 16/32).
// ---------------------------------------------------------------------------
__global__ __launch_bounds__(256) void k2_zmix(
    const float* __restrict__ policies, const float* __restrict__ actions,
    const float* __restrict__ noise, const float* __restrict__ w_in,
    float* __restrict__ out)
{
    __shared__ float spi[NA][NACT];   // 8 KB
    __shared__ float sac[NA][NACT];   // 8 KB
    __shared__ float sww[4][NA];      // 512 B

    const int blk = blockIdx.x;       // 0..2047
    const int b   = blk >> 3;         // graph
    const int tid = threadIdx.x;

    {
        const float4* ps = reinterpret_cast<const float4*>(policies + (size_t)b * 2048);
        const float4* as = reinterpret_cast<const float4*>(actions  + (size_t)b * 2048);
        float4* pd = reinterpret_cast<float4*>(&spi[0][0]);
        float4* ad = reinterpret_cast<float4*>(&sac[0][0]);
        pd[tid] = ps[tid]; pd[tid + 256] = ps[tid + 256];
        ad[tid] = as[tid]; ad[tid + 256] = as[tid + 256];
        if (tid < 128) sww[tid >> 5][tid & 31] = w_in[(size_t)blk * 128 + tid];
    }
    __syncthreads();

    const int wv   = tid >> 6;    // wave -> dst row
    const int lane = tid & 63;
    const int qq   = lane >> 4;   // t-quarter
    const int cg   = lane & 15;   // col group (4 floats)
    const int c0   = cg * 4;
    const size_t gr = (size_t)blk * 4 + wv;   // = b*32 + i

    float4* out4 = reinterpret_cast<float4*>(out) + gr * 1536;

    float S0 = 0.f, S1 = 0.f, S2 = 0.f, S3 = 0.f;
    float y[8][4];
    const float* nzb = noise + (gr * 32 + qq * 8) * 64 + c0;
#pragma unroll
    for (int tt = 0; tt < 8; ++tt) {
        const int t = qq * 8 + tt;
        const float wt = sww[wv][t];
        const float4 p4 = *reinterpret_cast<const float4*>(&spi[t][c0]);
        const float4 a4 = *reinterpret_cast<const float4*>(&sac[t][c0]);
        const float4 n4 = *reinterpret_cast<const float4*>(nzb + tt * 64);
        float z;
        z = fmaf(wt, a4.x - p4.x, p4.x) + n4.x; S0 += z; y[tt][0] = p4.x - z;
        z = fmaf(wt, a4.y - p4.y, p4.y) + n4.y; S1 += z; y[tt][1] = p4.y - z;
        z = fmaf(wt, a4.z - p4.z, p4.z) + n4.z; S2 += z; y[tt][2] = p4.z - z;
        z = fmaf(wt, a4.w - p4.w, p4.w) + n4.w; S3 += z; y[tt][3] = p4.w - z;
    }
    S0 += __shfl_xor(S0, 16); S0 += __shfl_xor(S0, 32);
    S1 += __shfl_xor(S1, 16); S1 += __shfl_xor(S1, 32);
    S2 += __shfl_xor(S2, 16); S2 += __shfl_xor(S2, 32);
    S3 += __shfl_xor(S3, 16); S3 += __shfl_xor(S3, 32);

#pragma unroll
    for (int tt = 0; tt < 8; ++tt) {
        const int t = qq * 8 + tt;
        float4 o;
        o.x = (S0 + y[tt][0]) * (1.0f / NA);
        o.y = (S1 + y[tt][1]) * (1.0f / NA);
        o.z = (S2 + y[tt][2]) * (1.0f / NA);
        o.w = (S3 + y[tt][3]) * (1.0f / NA);
        out4[t * 48 + 32 + cg] = o;
    }
}

extern "C" void kernel_launch(void* const* d_in, const int* in_sizes, int n_in,
                              void* d_out, int out_size, void* d_ws, size_t ws_size,
                              hipStream_t stream) {
    const float* h        = (const float*)d_in[0];
    const float* policies = (const float*)d_in[1];
    const float* actions  = (const float*)d_in[2];
    const float* obs_proc = (const float*)d_in[3];
    const float* noise    = (const float*)d_in[4];
    const float* Wk       = (const float*)d_in[5];
    const float* bk       = (const float*)d_in[6];
    const float* Wq       = (const float*)d_in[7];
    const float* bq       = (const float*)d_in[8];

    float* out = (float*)d_out;
    float* obs_final = out;                                      // [8192,32,192]
    float* w_out = out + (size_t)NB * NA * NA * (NIN + NACT);    // [8192,32,1]

    k1_qk_obscopy<<<NB + NB * NA, 256, 0, stream>>>(h, Wk, bk, Wq, bq, obs_proc,
                                                    obs_final, w_out);
    k2_zmix<<<NB * NA / 4, 256, 0, stream>>>(policies, actions, noise, w_out,
                                             obs_final);
}